// Round 5
// baseline (163.100 us; speedup 1.0000x reference)
//
#include <hip/hip_runtime.h>
#include <stdint.h>

#pragma clang fp contract(off)

#define N_ANCH 90000
#define M_TOP  1024          // selection scope (rank scatter); walk fast path covers M_L=512
#define M_L    512           // LDS-mask walk scope; stop row ~330 for this input
#define NW_L   8             // mask words per row (M_L/64)
#define K_POST 300
#define CAP    2048          // compact capacity: M_TOP + threshold-bin slack (~400)
#define NHBINS 32768         // bins for (key>>16) - 0x8000 (valid keys always >= 0x8000)
#define WINB   0x3D00        // decode LDS hist window base: p >= ~0.031 -> ~99.3% of mass
#define WINSZ  768
#define DB     32            // decode blocks
#define MIN_SIZE (16.0f / 800.0f)
#define IOU_THR  0.7f

// ---- workspace layout (bytes) ----
// memset-zeroed region first: hist | cnt | sbox | sval
#define OFF_HIST  0                          // 32768*4 = 131072
#define OFF_CNT   131072                     // 64 B: [0]=cand count
#define OFF_SBOX  131136                     // 1024*16 = 16384
#define OFF_SVAL  147520                     // 1024*4  = 4096
#define MEMSET_SZ 151616
#define OFF_CAND  151616                     // 2048*8 = 16384
#define OFF_ROI   168000                     // 90000*16 = 1440000
#define OFF_KEYS  1608000                    // 90000*4 = 360000 (end 1968000)

// 1) decode boxes, objectness, sortable key; histogram with LDS-privatized hot window
__global__ void __launch_bounds__(1024)
decode_score_kernel(const float2* __restrict__ cls,
                    const float4* __restrict__ reg,
                    const float4* __restrict__ anc,
                    float4* __restrict__ roi,
                    unsigned* __restrict__ keys,
                    int* __restrict__ hist) {
    __shared__ int lh[WINSZ];
    int tid = threadIdx.x;
    for (int k = tid; k < WINSZ; k += 1024) lh[k] = 0;
    __syncthreads();

    for (int n = blockIdx.x * 1024 + tid; n < N_ANCH; n += DB * 1024) {
        float4 a = anc[n];
        float4 r = reg[n];
        float aw  = a.z - a.x;
        float ah  = a.w - a.y;
        float acx = (a.z + a.x) * 0.5f;
        float acy = (a.w + a.y) * 0.5f;
        float cx = r.x * aw + acx;
        float cy = r.y * ah + acy;
        float w  = expf(r.z) * aw;
        float h  = expf(r.w) * ah;
        float x1 = fminf(fmaxf(cx - w * 0.5f, 0.0f), 1.0f);
        float y1 = fminf(fmaxf(cy - h * 0.5f, 0.0f), 1.0f);
        float x2 = fminf(fmaxf(cx + w * 0.5f, 0.0f), 1.0f);
        float y2 = fminf(fmaxf(cy + h * 0.5f, 0.0f), 1.0f);
        roi[n] = make_float4(x1, y1, x2, y2);

        float2 c = cls[n];
        float m  = fmaxf(c.x, c.y);
        float e0 = expf(c.x - m);
        float e1 = expf(c.y - m);
        float p  = e1 / (e0 + e1);

        bool ok = ((x2 - x1) >= MIN_SIZE) && ((y2 - y1) >= MIN_SIZE);
        unsigned key = ok ? (__float_as_uint(p) ^ 0x80000000u) : 0u;  // monotone; invalid -> 0
        keys[n] = key;
        if (key != 0u) {
            int hb = (int)(key >> 16) - 0x8000;
            if (hb >= WINB) atomicAdd(&lh[hb - WINB], 1);   // hot window: LDS
            else            atomicAdd(&hist[hb], 1);        // cold tail (~0.7%)
        }
    }
    __syncthreads();
    for (int k = tid; k < WINSZ; k += 1024) {
        int v = lh[k];
        if (v) atomicAdd(&hist[WINB + k], v);
    }
}

// 2) fused threshold + compact (single block, 1024 threads)
__global__ void __launch_bounds__(1024)
thrcompact_kernel(const unsigned* __restrict__ keys,
                  const int* __restrict__ hist,
                  int* __restrict__ cnt,
                  unsigned long long* __restrict__ cand) {
    __shared__ int part[1024];
    __shared__ int scan[1024];
    __shared__ int s_sel, s_base, s_pos;
    __shared__ unsigned s_thr;
    __shared__ int s_bins[32];
    int t = threadIdx.x;
    if (t == 0) { s_sel = -1; s_pos = 0; }
    // chunk t sums 32 bins: [NHBINS-(t+1)*32, NHBINS-t*32), high -> low chunks
    const int4* h4 = (const int4*)(hist + (NHBINS - (t + 1) * 32));
    int ssum = 0;
#pragma unroll
    for (int q = 0; q < 8; ++q) { int4 x = h4[q]; ssum += x.x + x.y + x.z + x.w; }
    part[t] = ssum;
    scan[t] = ssum;
    __syncthreads();
    for (int off = 1; off < 1024; off <<= 1) {      // inclusive Hillis-Steele scan
        int add = (t >= off) ? scan[t - off] : 0;
        __syncthreads();
        scan[t] += add;
        __syncthreads();
    }
    int cumI = scan[t], cumB = cumI - part[t];
    if (cumB < M_TOP && cumI >= M_TOP) { s_sel = t; s_base = cumB; }
    __syncthreads();
    int cs = s_sel;
    if (cs >= 0 && t < 32) s_bins[t] = hist[NHBINS - 1 - cs * 32 - t];
    __syncthreads();
    if (t == 0) {
        unsigned thr = 0x80000000u;                 // fewer than M_TOP valid: take all valid
        if (cs >= 0) {
            int acc = s_base;
            for (int k = 0; k < 32; ++k) {
                acc += s_bins[k];
                if (acc >= M_TOP) {
                    thr = ((unsigned)(NHBINS - 1 - cs * 32 - k + 0x8000)) << 16;
                    break;
                }
            }
        }
        s_thr = thr;
    }
    __syncthreads();
    unsigned thr = s_thr;
    // compact: pack key<<32 | ~idx (descending => lower idx first on ties, matches top_k)
    const uint4* k4 = (const uint4*)keys;
    for (int g = t; g < N_ANCH / 4; g += 1024) {
        uint4 kv = k4[g];
        int n0 = g * 4;
        if (kv.x >= thr) { int p = atomicAdd(&s_pos, 1); if (p < CAP) cand[p] = ((unsigned long long)kv.x << 32) | (unsigned)(~(unsigned)n0); }
        if (kv.y >= thr) { int p = atomicAdd(&s_pos, 1); if (p < CAP) cand[p] = ((unsigned long long)kv.y << 32) | (unsigned)(~(unsigned)(n0 + 1)); }
        if (kv.z >= thr) { int p = atomicAdd(&s_pos, 1); if (p < CAP) cand[p] = ((unsigned long long)kv.z << 32) | (unsigned)(~(unsigned)(n0 + 2)); }
        if (kv.w >= thr) { int p = atomicAdd(&s_pos, 1); if (p < CAP) cand[p] = ((unsigned long long)kv.w << 32) | (unsigned)(~(unsigned)(n0 + 3)); }
    }
    __syncthreads();
    if (t == 0) cnt[0] = (s_pos < CAP) ? s_pos : CAP;
}

// 3) rank select: rank(i) = #{j : cand[j] > cand[i]} (keys unique) -> direct scatter.
__global__ void __launch_bounds__(1024)
rank_select_kernel(const unsigned long long* __restrict__ cand,
                   const int* __restrict__ cnt,
                   const float4* __restrict__ roi,
                   float4* __restrict__ sbox,
                   int* __restrict__ sval) {
    __shared__ unsigned long long s[CAP];    // 16 KB
    __shared__ int red[1024];
    int tid = threadIdx.x;
    int c = cnt[0];
    if (c > CAP) c = CAP;
    for (int k = tid; k < CAP; k += 1024) s[k] = (k < c) ? cand[k] : 0ULL;
    __syncthreads();
    int e = tid & 63;
    int slice = tid >> 6;                    // 0..15
    int i = blockIdx.x * 64 + e;
    unsigned long long v = (i < c) ? s[i] : 0ULL;
    int cnt_gt = 0;
    if (i < c) {
        int kbeg = slice * (CAP / 16);
        int kend = kbeg + (CAP / 16);
        if (kend > c) kend = c;
#pragma unroll 4
        for (int k = kbeg; k < kend; ++k)
            cnt_gt += (s[k] > v) ? 1 : 0;
    }
    red[tid] = cnt_gt;
    __syncthreads();
    if (slice == 0 && i < c) {
        int rank = 0;
#pragma unroll
        for (int q = 0; q < 16; ++q) rank += red[e + 64 * q];
        if (rank < M_TOP) {
            unsigned idx = ~((unsigned)v);
            sbox[rank] = roi[idx];
            sval[rank] = 1;
        }
    }
}

// 4) fused mask build (LDS) + serial greedy walk (wave 0) + output
__global__ void __launch_bounds__(1024)
maskwalk_kernel(const float4* __restrict__ sbox_g,
                const int* __restrict__ sval_g,
                float4* __restrict__ out) {
    __shared__ float4 sb[M_L];                         // 8 KB
    __shared__ float  sarea[M_L];                      // 2 KB
    __shared__ int    sv[M_L];                         // 2 KB
    __shared__ unsigned long long smask[M_L * NW_L];   // 32 KB
    __shared__ int s_keep[K_POST];
    __shared__ int s_kc;
    int tid = threadIdx.x;
    if (tid < M_L) {
        float4 b = sbox_g[tid];
        sb[tid] = b;
        sarea[tid] = (b.z - b.x) * (b.w - b.y);
        sv[tid] = sval_g[tid];
    }
    __syncthreads();
    // mask build: word wid = tid*4+q; row i = wid>>3, word w = wid&7; bit j>i & iou>thr
#pragma unroll
    for (int q = 0; q < 4; ++q) {
        int wid = (tid << 2) + q;
        int i = wid >> 3;
        int w = wid & 7;
        unsigned long long bits = 0;
        int j0 = w << 6;
        if (j0 + 63 > i) {                              // skip words fully below diagonal
            float4 bi = sb[i];
            float ai = sarea[i];
            for (int b = 0; b < 64; ++b) {
                int j = j0 + b;
                if (j > i) {
                    float4 bj = sb[j];
                    float xx1 = fmaxf(bi.x, bj.x);
                    float yy1 = fmaxf(bi.y, bj.y);
                    float xx2 = fminf(bi.z, bj.z);
                    float yy2 = fminf(bi.w, bj.w);
                    float ww = fmaxf(xx2 - xx1, 0.0f);
                    float hh = fmaxf(yy2 - yy1, 0.0f);
                    float inter = ww * hh;
                    float uni = ai + sarea[j] - inter;
                    float iou = inter / fmaxf(uni, 1e-12f);
                    if (iou > IOU_THR) bits |= 1ull << b;
                }
            }
        }
        smask[wid] = bits;
    }
    __syncthreads();
    if (tid < 64) {                                     // wave 0 walks
        int lane = tid;
        unsigned long long remv = 0;                    // lane w (<8) holds word w
#pragma unroll
        for (int w = 0; w < NW_L; ++w) {
            unsigned long long bm = __ballot(sv[(w << 6) + lane] == 0);
            if (lane == w) remv = bm;
        }
        int wsel = lane & 7;
        const int PF = 4;
        unsigned long long pf[PF];
#pragma unroll
        for (int d = 0; d < PF; ++d) pf[d] = smask[(d << 3) + wsel];
        int kc = 0;                                     // uniform
        bool done = false;                              // uniform
        for (int base = 0; base < M_L && !done; base += PF) {
#pragma unroll
            for (int u = 0; u < PF; ++u) {
                int i = base + u;
                if (!done) {
                    int widx = i >> 6;                  // uniform -> scalar readlane
                    unsigned lo = (unsigned)__builtin_amdgcn_readlane((int)(unsigned)remv, widx);
                    unsigned hi = (unsigned)__builtin_amdgcn_readlane((int)(unsigned)(remv >> 32), widx);
                    unsigned long long wv = ((unsigned long long)hi << 32) | lo;
                    if (!((wv >> (i & 63)) & 1ull)) {   // kept
                        if (lane == 0) s_keep[kc] = i;
                        remv |= pf[u];                  // lanes>=8 OR duplicate data, never read
                        ++kc;
                        if (kc >= K_POST) done = true;
                    }
                }
                int nr = (base + u + PF) & (M_L - 1);   // wrap to stay in-bounds
                pf[u] = smask[(nr << 3) + wsel];
            }
        }
        // cold fallback: rows [M_L, M_TOP) vs kept set (correctness only; not hit for this input)
        if (!done) {
            for (int i = M_L; i < M_TOP && kc < K_POST; ++i) {
                if (sval_g[i]) {
                    float4 bi = sbox_g[i];
                    float ai = (bi.z - bi.x) * (bi.w - bi.y);
                    bool any = false;
                    for (int k = lane; k < kc; k += 64) {
                        int ki = s_keep[k];
                        float4 bk = (ki < M_L) ? sb[ki] : sbox_g[ki];
                        float xx1 = fmaxf(bi.x, bk.x);
                        float yy1 = fmaxf(bi.y, bk.y);
                        float xx2 = fminf(bi.z, bk.z);
                        float yy2 = fminf(bi.w, bk.w);
                        float ww = fmaxf(xx2 - xx1, 0.0f);
                        float hh = fmaxf(yy2 - yy1, 0.0f);
                        float inter = ww * hh;
                        float ak = (bk.z - bk.x) * (bk.w - bk.y);
                        float uni = ai + ak - inter;
                        if (inter / fmaxf(uni, 1e-12f) > IOU_THR) any = true;
                    }
                    if (__ballot(any) == 0ull) {
                        if (lane == 0) s_keep[kc] = i;
                        ++kc;
                    }
                }
            }
        }
        if (lane == 0) s_kc = kc;
    }
    __syncthreads();
    int kc = s_kc;
    for (int j = tid; j < K_POST; j += 1024) {
        if (j < kc) {
            int idx = s_keep[j];
            out[j] = (idx < M_L) ? sb[idx] : sbox_g[idx];
        } else {
            out[j] = make_float4(0.f, 0.f, 0.f, 0.f);
        }
    }
}

extern "C" void kernel_launch(void* const* d_in, const int* in_sizes, int n_in,
                              void* d_out, int out_size, void* d_ws, size_t ws_size,
                              hipStream_t stream) {
    const float2* cls = (const float2*)d_in[0];   // (1,100,100,18) fp32 -> logit pairs
    const float4* reg = (const float4*)d_in[1];   // (1,90000,4)
    const float4* anc = (const float4*)d_in[2];   // (90000,4)
    float4* out = (float4*)d_out;                 // 300 x 4 fp32

    char* ws = (char*)d_ws;
    int*       hist = (int*)(ws + OFF_HIST);
    int*       cnt  = (int*)(ws + OFF_CNT);
    float4*    sbox = (float4*)(ws + OFF_SBOX);
    int*       sval = (int*)(ws + OFF_SVAL);
    unsigned long long* cand = (unsigned long long*)(ws + OFF_CAND);
    float4*    roi  = (float4*)(ws + OFF_ROI);
    unsigned*  keys = (unsigned*)(ws + OFF_KEYS);

    // ws re-poisoned 0xAA before every timed call: zero hist+cnt+sbox+sval every call
    hipMemsetAsync(ws, 0, MEMSET_SZ, stream);

    decode_score_kernel<<<DB, 1024, 0, stream>>>(cls, reg, anc, roi, keys, hist);
    thrcompact_kernel<<<1, 1024, 0, stream>>>(keys, hist, cnt, cand);
    rank_select_kernel<<<CAP / 64, 1024, 0, stream>>>(cand, cnt, roi, sbox, sval);
    maskwalk_kernel<<<1, 1024, 0, stream>>>(sbox, sval, out);
}